// Round 4
// baseline (881.255 us; speedup 1.0000x reference)
//
#include <hip/hip_runtime.h>

#define CCH 64     // channels
#define BPB 256    // bins per coarse bucket
#define NBMAX 1024 // max coarse buckets (M/BPB = 1024 here)
#define ELPB 4096  // elements per partition block

__device__ __forceinline__ float4 f4zero() { return make_float4(0.f, 0.f, 0.f, 0.f); }

// ---- P1: per-block histogram of coarse buckets (LDS atomics only) ----
__global__ void p1_hist(const int* __restrict__ os, int* __restrict__ cnt,
                        int total, int nblk, int nb) {
    __shared__ int hist[NBMAX];
    int tid = threadIdx.x;
    for (int b = tid; b < nb; b += 256) hist[b] = 0;
    __syncthreads();
    int start = blockIdx.x * ELPB;
    for (int i = 0; i < ELPB / 256; ++i) {
        int idx = start + i * 256 + tid;
        if (idx < total) atomicAdd(&hist[os[idx] >> 8], 1);
    }
    __syncthreads();
    for (int b = tid; b < nb; b += 256)
        cnt[b * nblk + blockIdx.x] = hist[b];
}

// ---- P2a: per-bucket exclusive scan across blocks (one wave per bucket) ----
__global__ void p2a_scan(int* __restrict__ cnt, int* __restrict__ btot,
                         int nblk, int nb) {
    int wid  = (blockIdx.x * blockDim.x + threadIdx.x) >> 6;
    int lane = threadIdx.x & 63;
    if (wid >= nb) return;
    int running = 0;
    for (int c = 0; c < nblk; c += 64) {
        int in_r = (c + lane < nblk);
        int idx = wid * nblk + c + lane;
        int v = in_r ? cnt[idx] : 0;
        int s = v;
        for (int d = 1; d < 64; d <<= 1) { int t = __shfl_up(s, d); if (lane >= d) s += t; }
        if (in_r) cnt[idx] = running + s - v;
        running += __shfl(s, 63);
    }
    if (lane == 0) btot[wid] = running;
}

// ---- P2b: exclusive scan of bucket totals -> base[]; base[nb] = total ----
__global__ void p2b_base(const int* __restrict__ btot, int* __restrict__ base, int nb) {
    __shared__ int wtot[16];
    int tid = threadIdx.x, lane = tid & 63, w = tid >> 6;
    int v = (tid < nb) ? btot[tid] : 0;
    int s = v;
    for (int d = 1; d < 64; d <<= 1) { int t = __shfl_up(s, d); if (lane >= d) s += t; }
    if (lane == 63) wtot[w] = s;
    __syncthreads();
    if (w == 0) {
        int wv = (lane < 16) ? wtot[lane] : 0;
        int ss = wv;
        for (int d = 1; d < 16; d <<= 1) { int t = __shfl_up(ss, d); if (lane >= d) ss += t; }
        if (lane < 16) wtot[lane] = ss - wv;
    }
    __syncthreads();
    if (tid < nb) base[tid] = s - v + wtot[w];
    if (tid == nb - 1) base[nb] = s + wtot[w];   // grand total
}

// ---- P3: place packed keys into compact per-bucket segments ----
// key = (o & 255) << 21 | n << 3 | j   (n < 2^18, j < 8)
__global__ void p3_scatter(const int* __restrict__ os, const int* __restrict__ cnt,
                           const int* __restrict__ base, int* __restrict__ ent,
                           int total, int nblk, int nb, int d1) {
    __shared__ int cursor[NBMAX];
    int tid = threadIdx.x, blk = blockIdx.x;
    for (int b = tid; b < nb; b += 256)
        cursor[b] = base[b] + cnt[b * nblk + blk];
    __syncthreads();
    int start = blk * ELPB;
    for (int i = 0; i < ELPB / 256; ++i) {
        int idx = start + i * 256 + tid;
        if (idx < total) {
            int o = os[idx];
            int n = idx / d1;
            int j = idx - n * d1;
            int key = ((o & (BPB - 1)) << 21) | (n << 3) | j;
            int d = atomicAdd(&cursor[o >> 8], 1);
            ent[d] = key;
        }
    }
}

// ---- P4: LDS-tile splat. One block per coarse bucket (256 bins x 64 ch). ----
__global__ void __launch_bounds__(256, 2)
p4_splat(const float* __restrict__ inp, const float* __restrict__ wsarr,
         const int* __restrict__ ent, const int* __restrict__ base,
         float* __restrict__ vals, int M, int d1) {
    __shared__ float tile[BPB * CCH];   // 64 KiB
    int tid = threadIdx.x, lane = tid & 63, w = tid >> 6;
    int bkt = blockIdx.x;
    float4* t4 = (float4*)tile;
    for (int i = tid; i < BPB * CCH / 4; i += 256) t4[i] = f4zero();
    __syncthreads();

    int s = base[bkt], e = base[bkt + 1];
    int len = e - s;
    int per = (len + 3) >> 2;             // split segment across 4 waves
    int wstart = s + w * per;
    int wend   = min(wstart + per, e);
    for (int p = wstart; p < wend; p += 64) {
        int cl = wend - p; if (cl > 64) cl = 64;
        int k = 0; float wt = 0.f;
        if (lane < cl) {
            k = ent[p + lane];                       // coalesced
            int n = (k >> 3) & 0x3FFFF;
            wt = wsarr[n * d1 + (k & 7)];
        }
        for (int i = 0; i < cl; ++i) {
            int   ki = __shfl(k, i);
            float wi = __shfl(wt, i);
            int n  = (ki >> 3) & 0x3FFFF;
            int bl = ki >> 21;
            float v = inp[(size_t)n * CCH + lane];   // coalesced 256B row
            atomicAdd(&tile[bl * CCH + lane], wi * v);  // LDS fp32 atomic, 2-way bank = free
        }
    }
    __syncthreads();
    int nbin = M - bkt * BPB; if (nbin > BPB) nbin = BPB;
    float4* v4 = (float4*)(vals + (size_t)bkt * BPB * CCH);
    int lim = nbin * CCH / 4;
    for (int i = tid; i < lim; i += 256) v4[i] = t4[i];
}

// ---- Blur: dst[m] = src[m] + 0.5*(src[n1-1] + src[n2-1]); 0 => zero row ----
__global__ void blur_kernel(const float4* __restrict__ src,
                            const int2* __restrict__ bn,  // [M], 1-based pairs
                            float4* __restrict__ dst, int M) {
    int t = blockIdx.x * blockDim.x + threadIdx.x;
    int m = t >> 4;
    int l = t & 15;
    if (m >= M) return;
    int2 nn = bn[m];
    float4 a  = src[(size_t)m * 16 + l];
    float4 b1 = (nn.x > 0) ? src[(size_t)(nn.x - 1) * 16 + l] : f4zero();
    float4 b2 = (nn.y > 0) ? src[(size_t)(nn.y - 1) * 16 + l] : f4zero();
    float4 r;
    r.x = a.x + 0.5f * (b1.x + b2.x);
    r.y = a.y + 0.5f * (b1.y + b2.y);
    r.z = a.z + 0.5f * (b1.z + b2.z);
    r.w = a.w + 0.5f * (b1.w + b2.w);
    dst[(size_t)m * 16 + l] = r;
}

// ---- Slice: out[n] = alpha * sum_j ws[n,j] * vals[os[n,j]] ----
__global__ void slice_kernel(const float4* __restrict__ vals4,
                             const float* __restrict__ ws,
                             const int* __restrict__ os,
                             float4* __restrict__ out4, int N, float alpha) {
    int t = blockIdx.x * blockDim.x + threadIdx.x;
    int n = t >> 4;
    int l = t & 15;
    if (n >= N) return;
    float4 acc = f4zero();
#pragma unroll
    for (int j = 0; j < 6; ++j) {
        float w = ws[n * 6 + j];
        int   o = os[n * 6 + j];
        float4 v = vals4[(size_t)o * 16 + l];
        acc.x += w * v.x; acc.y += w * v.y; acc.z += w * v.z; acc.w += w * v.w;
    }
    acc.x *= alpha; acc.y *= alpha; acc.z *= alpha; acc.w *= alpha;
    out4[(size_t)n * 16 + l] = acc;
}

extern "C" void kernel_launch(void* const* d_in, const int* in_sizes, int n_in,
                              void* d_out, int out_size, void* d_ws, size_t ws_size,
                              hipStream_t stream) {
    const float* inp = (const float*)d_in[0];
    const float* ws  = (const float*)d_in[1];
    const int*   os  = (const int*)d_in[2];
    const int*   bn  = (const int*)d_in[3];

    const int N  = in_sizes[0] / CCH;           // 262144
    const int d1 = in_sizes[1] / N;             // 6
    const int M  = in_sizes[3] / (d1 * 2);      // 262144
    const float alpha = 1.0f / (1.0f + exp2f(-(float)(d1 - 1)));

    float* A = (float*)d_ws;    // vals buffer A (M*CCH floats = 64 MiB)

    const int total = N * d1;                       // 1572864
    const int NB    = (M + BPB - 1) / BPB;          // 1024
    const int NBLK  = (total + ELPB - 1) / ELPB;    // 384

    // Scratch inside d_out (dead until blur pass 1 overwrites it): ~8 MB
    int* ent  = (int*)d_out;          // [total]
    int* cnt  = ent + total;          // [NB*NBLK]
    int* btot = cnt + NB * NBLK;      // [NB]
    int* base = btot + NB;            // [NB+1]

    // --- splat phase (no global atomics) ---
    p1_hist   <<<NBLK, 256, 0, stream>>>(os, cnt, total, NBLK, NB);
    p2a_scan  <<<(NB * 64 + 255) / 256, 256, 0, stream>>>(cnt, btot, NBLK, NB);
    p2b_base  <<<1, 1024, 0, stream>>>(btot, base, NB);
    p3_scatter<<<NBLK, 256, 0, stream>>>(os, cnt, base, ent, total, NBLK, NB, d1);
    p4_splat  <<<NB, 256, 0, stream>>>(inp, ws, ent, base, A, M, d1);

    // --- blur phase: 6 ping-pong passes (A -> B -> A ... -> A) ---
    const int mblocks16 = (M * 16 + 255) / 256;
    const float* src = A;
    float* dst = (float*)d_out;
    for (int j = 0; j < d1; ++j) {
        blur_kernel<<<mblocks16, 256, 0, stream>>>(
            (const float4*)src, (const int2*)(bn + (size_t)j * M * 2), (float4*)dst, M);
        float* tmp = (float*)src; src = dst; dst = tmp;
    }

    // d1=6 passes (even) -> final vals in A; slice reads A, writes d_out
    const int nblocks16 = (N * 16 + 255) / 256;
    slice_kernel<<<nblocks16, 256, 0, stream>>>(
        (const float4*)src, ws, os, (float4*)d_out, N, alpha);
}

// Round 5
// 430.724 us; speedup vs baseline: 2.0460x; 2.0460x over previous
//
#include <hip/hip_runtime.h>

#define CCH 64     // channels
#define CAP 32     // max entries per fine bin (Poisson(6): P(>32) ~ 1e-16)
#define BPB 256    // fine bins per coarse bucket
#define NBMAX 1024 // max coarse buckets (M/BPB = 1024 here)
#define ELPB 4096  // elements per partition block

__device__ __forceinline__ float4 f4zero() { return make_float4(0.f, 0.f, 0.f, 0.f); }

// ---- P1: per-block histogram of coarse buckets (LDS atomics only) ----
__global__ void p1_hist(const int* __restrict__ os, int* __restrict__ cnt,
                        int total, int nblk, int nb) {
    __shared__ int hist[NBMAX];
    int tid = threadIdx.x;
    for (int b = tid; b < nb; b += 256) hist[b] = 0;
    __syncthreads();
    int start = blockIdx.x * ELPB;
    for (int i = 0; i < ELPB / 256; ++i) {
        int idx = start + i * 256 + tid;
        if (idx < total) atomicAdd(&hist[os[idx] >> 8], 1);
    }
    __syncthreads();
    for (int b = tid; b < nb; b += 256)
        cnt[b * nblk + blockIdx.x] = hist[b];
}

// ---- P2a: per-bucket exclusive scan across blocks (one wave per bucket) ----
__global__ void p2a_scan(int* __restrict__ cnt, int* __restrict__ btot,
                         int nblk, int nb) {
    int wid  = (blockIdx.x * blockDim.x + threadIdx.x) >> 6;
    int lane = threadIdx.x & 63;
    if (wid >= nb) return;
    int running = 0;
    for (int c = 0; c < nblk; c += 64) {
        int in_r = (c + lane < nblk);
        int idx = wid * nblk + c + lane;
        int v = in_r ? cnt[idx] : 0;
        int s = v;
        for (int d = 1; d < 64; d <<= 1) { int t = __shfl_up(s, d); if (lane >= d) s += t; }
        if (in_r) cnt[idx] = running + s - v;
        running += __shfl(s, 63);
    }
    if (lane == 0) btot[wid] = running;
}

// ---- P2b: exclusive scan of bucket totals -> base[]; base[nb] = total ----
__global__ void p2b_base(const int* __restrict__ btot, int* __restrict__ base, int nb) {
    __shared__ int wtot[16];
    int tid = threadIdx.x, lane = tid & 63, w = tid >> 6;
    int v = (tid < nb) ? btot[tid] : 0;
    int s = v;
    for (int d = 1; d < 64; d <<= 1) { int t = __shfl_up(s, d); if (lane >= d) s += t; }
    if (lane == 63) wtot[w] = s;
    __syncthreads();
    if (w == 0) {
        int wv = (lane < 16) ? wtot[lane] : 0;
        int ss = wv;
        for (int d = 1; d < 16; d <<= 1) { int t = __shfl_up(ss, d); if (lane >= d) ss += t; }
        if (lane < 16) wtot[lane] = ss - wv;
    }
    __syncthreads();
    if (tid < nb) base[tid] = s - v + wtot[w];
    if (tid == nb - 1) base[nb] = s + wtot[w];   // grand total
}

// ---- P3: place packed keys into compact per-bucket segments ----
// key = (o & 255) << 21 | n << 3 | j   (n < 2^18, j < 8)
__global__ void p3_scatter(const int* __restrict__ os, const int* __restrict__ cnt,
                           const int* __restrict__ base, int* __restrict__ ent,
                           int total, int nblk, int nb, int d1) {
    __shared__ int cursor[NBMAX];
    int tid = threadIdx.x, blk = blockIdx.x;
    for (int b = tid; b < nb; b += 256)
        cursor[b] = base[b] + cnt[b * nblk + blk];
    __syncthreads();
    int start = blk * ELPB;
    for (int i = 0; i < ELPB / 256; ++i) {
        int idx = start + i * 256 + tid;
        if (idx < total) {
            int o = os[idx];
            int n = idx / d1;
            int j = idx - n * d1;
            int key = ((o & (BPB - 1)) << 21) | (n << 3) | j;
            int d = atomicAdd(&cursor[o >> 8], 1);
            ent[d] = key;
        }
    }
}

// ---- P3b: fine re-bin within each bucket. LDS cursors; all global stores
// land inside this bucket's 32KB CAP window (L2-resident). ----
__global__ void p3b_fine(const int* __restrict__ ent, const int* __restrict__ base,
                         int* __restrict__ ent2, int* __restrict__ cnt2) {
    __shared__ int cur[BPB];
    int tid = threadIdx.x;
    int bkt = blockIdx.x;
    if (tid < BPB) cur[tid] = 0;
    __syncthreads();
    int s = base[bkt], e = base[bkt + 1];
    for (int p = s + tid; p < e; p += 256) {
        int key = ent[p];                 // coalesced
        int bl  = key >> 21;              // fine bin within bucket
        int pos = atomicAdd(&cur[bl], 1); // LDS-scope atomic
        if (pos < CAP)
            ent2[((size_t)bkt * BPB + bl) * CAP + pos] = key & 0x1FFFFF;
    }
    __syncthreads();
    if (tid < BPB) cnt2[bkt * BPB + tid] = cur[tid];
}

// ---- Gather-splat: 16 lanes per lattice row (float4/lane), 4 rows/wave.
// Entries+weights prefetched lane-parallel, broadcast via shuffle; all inp
// row gathers independent -> high memory-level parallelism. ----
__global__ void gather_splat_kernel(const float4* __restrict__ inp4,
                                    const float* __restrict__ ws,
                                    const int* __restrict__ cnt,
                                    const int* __restrict__ entries,
                                    float4* __restrict__ vals4, int M) {
    int t = blockIdx.x * blockDim.x + threadIdx.x;
    int o = t >> 4;           // lattice row
    int l = t & 15;           // float4 slot within row
    if (o >= M) return;
    int lane  = threadIdx.x & 63;
    int gbase = lane & 48;    // first lane of this 16-lane group

    int k = cnt[o];
    if (k > CAP) k = CAP;
    const int* bucket = entries + (size_t)o * CAP;

    int e_lo = 0; float w_lo = 0.f;
    if (l < k)      { e_lo = bucket[l];
                      w_lo = ws[(e_lo >> 3) * 6 + (e_lo & 7)]; }
    int e_hi = 0; float w_hi = 0.f;
    if (l + 16 < k) { e_hi = bucket[l + 16];
                      w_hi = ws[(e_hi >> 3) * 6 + (e_hi & 7)]; }

    float4 acc = f4zero();
    int klo = k < 16 ? k : 16;
    for (int i = 0; i < klo; ++i) {      // uniform within each 16-lane group
        int   e = __shfl(e_lo, gbase + i);
        float w = __shfl(w_lo, gbase + i);
        float4 v = inp4[(size_t)(e >> 3) * 16 + l];
        acc.x += w * v.x; acc.y += w * v.y; acc.z += w * v.z; acc.w += w * v.w;
    }
    for (int i = 16; i < k; ++i) {       // rare tail (k > 16)
        int   e = __shfl(e_hi, gbase + (i - 16));
        float w = __shfl(w_hi, gbase + (i - 16));
        float4 v = inp4[(size_t)(e >> 3) * 16 + l];
        acc.x += w * v.x; acc.y += w * v.y; acc.z += w * v.z; acc.w += w * v.w;
    }
    vals4[(size_t)o * 16 + l] = acc;     // single non-atomic row write
}

// ---- Blur: dst[m] = src[m] + 0.5*(src[n1-1] + src[n2-1]); 0 => zero row ----
__global__ void blur_kernel(const float4* __restrict__ src,
                            const int2* __restrict__ bn,  // [M], 1-based pairs
                            float4* __restrict__ dst, int M) {
    int t = blockIdx.x * blockDim.x + threadIdx.x;
    int m = t >> 4;
    int l = t & 15;
    if (m >= M) return;
    int2 nn = bn[m];
    float4 a  = src[(size_t)m * 16 + l];
    float4 b1 = (nn.x > 0) ? src[(size_t)(nn.x - 1) * 16 + l] : f4zero();
    float4 b2 = (nn.y > 0) ? src[(size_t)(nn.y - 1) * 16 + l] : f4zero();
    float4 r;
    r.x = a.x + 0.5f * (b1.x + b2.x);
    r.y = a.y + 0.5f * (b1.y + b2.y);
    r.z = a.z + 0.5f * (b1.z + b2.z);
    r.w = a.w + 0.5f * (b1.w + b2.w);
    dst[(size_t)m * 16 + l] = r;
}

// ---- Slice: out[n] = alpha * sum_j ws[n,j] * vals[os[n,j]] ----
__global__ void slice_kernel(const float4* __restrict__ vals4,
                             const float* __restrict__ ws,
                             const int* __restrict__ os,
                             float4* __restrict__ out4, int N, float alpha) {
    int t = blockIdx.x * blockDim.x + threadIdx.x;
    int n = t >> 4;
    int l = t & 15;
    if (n >= N) return;
    float4 acc = f4zero();
#pragma unroll
    for (int j = 0; j < 6; ++j) {
        float w = ws[n * 6 + j];
        int   o = os[n * 6 + j];
        float4 v = vals4[(size_t)o * 16 + l];
        acc.x += w * v.x; acc.y += w * v.y; acc.z += w * v.z; acc.w += w * v.w;
    }
    acc.x *= alpha; acc.y *= alpha; acc.z *= alpha; acc.w *= alpha;
    out4[(size_t)n * 16 + l] = acc;
}

extern "C" void kernel_launch(void* const* d_in, const int* in_sizes, int n_in,
                              void* d_out, int out_size, void* d_ws, size_t ws_size,
                              hipStream_t stream) {
    const float* inp = (const float*)d_in[0];
    const float* ws  = (const float*)d_in[1];
    const int*   os  = (const int*)d_in[2];
    const int*   bn  = (const int*)d_in[3];

    const int N  = in_sizes[0] / CCH;           // 262144
    const int d1 = in_sizes[1] / N;             // 6
    const int M  = in_sizes[3] / (d1 * 2);      // 262144
    const float alpha = 1.0f / (1.0f + exp2f(-(float)(d1 - 1)));

    float* A = (float*)d_ws;    // vals buffer A (M*CCH floats = 64 MiB)

    const int total = N * d1;                       // 1572864
    const int NB    = (M + BPB - 1) / BPB;          // 1024
    const int NBLK  = (total + ELPB - 1) / ELPB;    // 384

    // Scratch inside d_out (dead until blur pass 1 overwrites it), ~43 MB:
    int* ent  = (int*)d_out;          // [total]          6.3 MB
    int* cnt  = ent + total;          // [NB*NBLK]        1.6 MB
    int* btot = cnt + NB * NBLK;      // [NB]
    int* base = btot + NB;            // [NB+1]
    int* ent2 = base + NB + 1;        // [M*CAP]         33.5 MB
    int* cnt2 = ent2 + (size_t)M * CAP; // [M]            1.0 MB

    // --- splat phase (no global atomics) ---
    p1_hist   <<<NBLK, 256, 0, stream>>>(os, cnt, total, NBLK, NB);
    p2a_scan  <<<(NB * 64 + 255) / 256, 256, 0, stream>>>(cnt, btot, NBLK, NB);
    p2b_base  <<<1, 1024, 0, stream>>>(btot, base, NB);
    p3_scatter<<<NBLK, 256, 0, stream>>>(os, cnt, base, ent, total, NBLK, NB, d1);
    p3b_fine  <<<NB, 256, 0, stream>>>(ent, base, ent2, cnt2);

    const int mblocks16 = (M * 16 + 255) / 256;
    gather_splat_kernel<<<mblocks16, 256, 0, stream>>>(
        (const float4*)inp, ws, cnt2, ent2, (float4*)A, M);

    // --- blur phase: 6 ping-pong passes (A -> B -> A ... -> A) ---
    const float* src = A;
    float* dst = (float*)d_out;
    for (int j = 0; j < d1; ++j) {
        blur_kernel<<<mblocks16, 256, 0, stream>>>(
            (const float4*)src, (const int2*)(bn + (size_t)j * M * 2), (float4*)dst, M);
        float* tmp = (float*)src; src = dst; dst = tmp;
    }

    // d1=6 passes (even) -> final vals in A; slice reads A, writes d_out
    const int nblocks16 = (N * 16 + 255) / 256;
    slice_kernel<<<nblocks16, 256, 0, stream>>>(
        (const float4*)src, ws, os, (float4*)d_out, N, alpha);
}

// Round 6
// 407.929 us; speedup vs baseline: 2.1603x; 1.0559x over previous
//
#include <hip/hip_runtime.h>

#define CCH 64     // channels
#define BPB 256    // fine bins per coarse bucket
#define NBMAX 1024 // max coarse buckets (M/BPB = 1024 here)
#define ELPB 4096  // elements per partition block

__device__ __forceinline__ float4 f4zero() { return make_float4(0.f, 0.f, 0.f, 0.f); }

// ---- P1: per-block histogram of coarse buckets (LDS atomics only) ----
__global__ void p1_hist(const int* __restrict__ os, int* __restrict__ cnt,
                        int total, int nblk, int nb) {
    __shared__ int hist[NBMAX];
    int tid = threadIdx.x;
    for (int b = tid; b < nb; b += 256) hist[b] = 0;
    __syncthreads();
    int start = blockIdx.x * ELPB;
    for (int i = 0; i < ELPB / 256; ++i) {
        int idx = start + i * 256 + tid;
        if (idx < total) atomicAdd(&hist[os[idx] >> 8], 1);
    }
    __syncthreads();
    for (int b = tid; b < nb; b += 256)
        cnt[b * nblk + blockIdx.x] = hist[b];
}

// ---- P2a: per-bucket exclusive scan across blocks (one wave per bucket) ----
__global__ void p2a_scan(int* __restrict__ cnt, int* __restrict__ btot,
                         int nblk, int nb) {
    int wid  = (blockIdx.x * blockDim.x + threadIdx.x) >> 6;
    int lane = threadIdx.x & 63;
    if (wid >= nb) return;
    int running = 0;
    for (int c = 0; c < nblk; c += 64) {
        int in_r = (c + lane < nblk);
        int idx = wid * nblk + c + lane;
        int v = in_r ? cnt[idx] : 0;
        int s = v;
        for (int d = 1; d < 64; d <<= 1) { int t = __shfl_up(s, d); if (lane >= d) s += t; }
        if (in_r) cnt[idx] = running + s - v;
        running += __shfl(s, 63);
    }
    if (lane == 0) btot[wid] = running;
}

// ---- P2b: exclusive scan of bucket totals -> base[]; base[nb] = total ----
__global__ void p2b_base(const int* __restrict__ btot, int* __restrict__ base, int nb) {
    __shared__ int wtot[16];
    int tid = threadIdx.x, lane = tid & 63, w = tid >> 6;
    int v = (tid < nb) ? btot[tid] : 0;
    int s = v;
    for (int d = 1; d < 64; d <<= 1) { int t = __shfl_up(s, d); if (lane >= d) s += t; }
    if (lane == 63) wtot[w] = s;
    __syncthreads();
    if (w == 0) {
        int wv = (lane < 16) ? wtot[lane] : 0;
        int ss = wv;
        for (int d = 1; d < 16; d <<= 1) { int t = __shfl_up(ss, d); if (lane >= d) ss += t; }
        if (lane < 16) wtot[lane] = ss - wv;
    }
    __syncthreads();
    if (tid < nb) base[tid] = s - v + wtot[w];
    if (tid == nb - 1) base[nb] = s + wtot[w];   // grand total
}

// ---- P3: place packed (key, weight) into compact coarse-bucket segments ----
// key = (o & 255) << 18 | n   (n < 2^18); weight read SEQUENTIALLY from ws[idx]
__global__ void p3_scatter(const int* __restrict__ os, const float* __restrict__ ws,
                           const int* __restrict__ cnt, const int* __restrict__ base,
                           int2* __restrict__ ent, int total, int nblk, int nb, int d1) {
    __shared__ int cursor[NBMAX];
    int tid = threadIdx.x, blk = blockIdx.x;
    for (int b = tid; b < nb; b += 256)
        cursor[b] = base[b] + cnt[b * nblk + blk];
    __syncthreads();
    int start = blk * ELPB;
    for (int i = 0; i < ELPB / 256; ++i) {
        int idx = start + i * 256 + tid;
        if (idx < total) {
            int o = os[idx];
            int n = idx / d1;            // magic-mul
            float wv = ws[idx];          // sequential, coalesced
            int key = ((o & (BPB - 1)) << 18) | n;
            int d = atomicAdd(&cursor[o >> 8], 1);
            ent[d] = make_int2(key, __float_as_int(wv));
        }
    }
}

// ---- P3b: fine counting-sort within each bucket -> compact ent3 + fbase ----
__global__ void p3b_fine(const int2* __restrict__ ent, const int* __restrict__ base,
                         int2* __restrict__ ent3, int* __restrict__ fbase,
                         int M, int nb) {
    __shared__ int cur[BPB];
    __shared__ int wsum[4];
    int tid = threadIdx.x, lane = tid & 63, w = tid >> 6;
    int bkt = blockIdx.x;
    cur[tid] = 0;
    __syncthreads();
    int s = base[bkt], e = base[bkt + 1];
    for (int p = s + tid; p < e; p += 256)
        atomicAdd(&cur[ent[p].x >> 18], 1);
    __syncthreads();
    // exclusive scan of cur[0..255]
    int v = cur[tid];
    int sc = v;
    for (int d = 1; d < 64; d <<= 1) { int t = __shfl_up(sc, d); if (lane >= d) sc += t; }
    if (lane == 63) wsum[w] = sc;
    __syncthreads();
    int woff = 0;
    for (int i = 0; i < w; ++i) woff += wsum[i];
    int excl = sc - v + woff;
    fbase[bkt * BPB + tid] = s + excl;
    __syncthreads();
    cur[tid] = excl;                    // reuse as intra-segment cursor
    __syncthreads();
    for (int p = s + tid; p < e; p += 256) {
        int2 kv = ent[p];
        int bl = kv.x >> 18;
        int pos = atomicAdd(&cur[bl], 1);          // LDS-scope
        ent3[s + pos] = make_int2(kv.x & 0x3FFFF, kv.y);
    }
    if (bkt == 0 && tid == 0) fbase[M] = base[nb];
}

// ---- Gather-splat: 16 lanes per lattice row (float4/lane), 4 rows/wave.
// Compact entries carry (n, w) together: one coalesced int2 prefetch,
// then k independent 256B inp row gathers broadcast via shuffle. ----
__global__ void gather_splat_kernel(const float4* __restrict__ inp4,
                                    const int2* __restrict__ ent3,
                                    const int* __restrict__ fbase,
                                    float4* __restrict__ vals4, int M) {
    int t = blockIdx.x * blockDim.x + threadIdx.x;
    int o = t >> 4;           // lattice row
    int l = t & 15;           // float4 slot within row
    if (o >= M) return;
    int lane  = threadIdx.x & 63;
    int gbase = lane & 48;    // first lane of this 16-lane group

    int s = fbase[o];
    int k = fbase[o + 1] - s;
    const int2* bucket = ent3 + s;

    int2 kv  = make_int2(0, 0);
    int2 kvh = make_int2(0, 0);
    if (l < k)      kv  = bucket[l];
    if (l + 16 < k) kvh = bucket[l + 16];

    float4 acc = f4zero();
    int klo = k < 16 ? k : 16;
    for (int i = 0; i < klo; ++i) {      // uniform within each 16-lane group
        int   n = __shfl(kv.x, gbase + i);
        float w = __int_as_float(__shfl(kv.y, gbase + i));
        float4 v = inp4[(size_t)n * 16 + l];
        acc.x += w * v.x; acc.y += w * v.y; acc.z += w * v.z; acc.w += w * v.w;
    }
    int khi = k < 32 ? k : 32;
    for (int i = 16; i < khi; ++i) {     // tail (16 < k <= 32), rare
        int   n = __shfl(kvh.x, gbase + (i - 16));
        float w = __int_as_float(__shfl(kvh.y, gbase + (i - 16)));
        float4 v = inp4[(size_t)n * 16 + l];
        acc.x += w * v.x; acc.y += w * v.y; acc.z += w * v.z; acc.w += w * v.w;
    }
    for (int i = 32; i < k; ++i) {       // fully general tail (k > 32), ~never
        int2 kvx = bucket[i];            // broadcast load
        float w = __int_as_float(kvx.y);
        float4 v = inp4[(size_t)kvx.x * 16 + l];
        acc.x += w * v.x; acc.y += w * v.y; acc.z += w * v.z; acc.w += w * v.w;
    }
    vals4[(size_t)o * 16 + l] = acc;     // single non-atomic row write
}

// ---- Blur: dst[m] = src[m] + 0.5*(src[n1-1] + src[n2-1]); 0 => zero row ----
__global__ void blur_kernel(const float4* __restrict__ src,
                            const int2* __restrict__ bn,  // [M], 1-based pairs
                            float4* __restrict__ dst, int M) {
    int t = blockIdx.x * blockDim.x + threadIdx.x;
    int m = t >> 4;
    int l = t & 15;
    if (m >= M) return;
    int2 nn = bn[m];
    float4 a  = src[(size_t)m * 16 + l];
    float4 b1 = (nn.x > 0) ? src[(size_t)(nn.x - 1) * 16 + l] : f4zero();
    float4 b2 = (nn.y > 0) ? src[(size_t)(nn.y - 1) * 16 + l] : f4zero();
    float4 r;
    r.x = a.x + 0.5f * (b1.x + b2.x);
    r.y = a.y + 0.5f * (b1.y + b2.y);
    r.z = a.z + 0.5f * (b1.z + b2.z);
    r.w = a.w + 0.5f * (b1.w + b2.w);
    dst[(size_t)m * 16 + l] = r;
}

// ---- Slice: out[n] = alpha * sum_j ws[n,j] * vals[os[n,j]] ----
__global__ void slice_kernel(const float4* __restrict__ vals4,
                             const float* __restrict__ ws,
                             const int* __restrict__ os,
                             float4* __restrict__ out4, int N, float alpha) {
    int t = blockIdx.x * blockDim.x + threadIdx.x;
    int n = t >> 4;
    int l = t & 15;
    if (n >= N) return;
    float4 acc = f4zero();
#pragma unroll
    for (int j = 0; j < 6; ++j) {
        float w = ws[n * 6 + j];
        int   o = os[n * 6 + j];
        float4 v = vals4[(size_t)o * 16 + l];
        acc.x += w * v.x; acc.y += w * v.y; acc.z += w * v.z; acc.w += w * v.w;
    }
    acc.x *= alpha; acc.y *= alpha; acc.z *= alpha; acc.w *= alpha;
    out4[(size_t)n * 16 + l] = acc;
}

extern "C" void kernel_launch(void* const* d_in, const int* in_sizes, int n_in,
                              void* d_out, int out_size, void* d_ws, size_t ws_size,
                              hipStream_t stream) {
    const float* inp = (const float*)d_in[0];
    const float* ws  = (const float*)d_in[1];
    const int*   os  = (const int*)d_in[2];
    const int*   bn  = (const int*)d_in[3];

    const int N  = in_sizes[0] / CCH;           // 262144
    const int d1 = in_sizes[1] / N;             // 6
    const int M  = in_sizes[3] / (d1 * 2);      // 262144
    const float alpha = 1.0f / (1.0f + exp2f(-(float)(d1 - 1)));

    float* A = (float*)d_ws;    // vals buffer A (M*CCH floats = 64 MiB)

    const int total = N * d1;                       // 1572864
    const int NB    = (M + BPB - 1) / BPB;          // 1024
    const int NBLK  = (total + ELPB - 1) / ELPB;    // 384

    // Scratch inside d_out (dead until blur pass 1 overwrites it), ~28 MB:
    int*  scratch = (int*)d_out;
    int2* ent   = (int2*)scratch;                   // [total] int2
    int*  cnt   = scratch + 2 * (size_t)total;      // [NB*NBLK]
    int*  btot  = cnt + NB * NBLK;                  // [NB]
    int*  base  = btot + NB;                        // [NB+1]
    int*  fbase = base + NB + 1;                    // [M+1]
    int2* ent3  = (int2*)(fbase + M + 1);           // [total] int2 (even-int offset)

    // --- splat phase (no global atomics, exact compact sort) ---
    p1_hist   <<<NBLK, 256, 0, stream>>>(os, cnt, total, NBLK, NB);
    p2a_scan  <<<(NB * 64 + 255) / 256, 256, 0, stream>>>(cnt, btot, NBLK, NB);
    p2b_base  <<<1, 1024, 0, stream>>>(btot, base, NB);
    p3_scatter<<<NBLK, 256, 0, stream>>>(os, ws, cnt, base, ent, total, NBLK, NB, d1);
    p3b_fine  <<<NB, 256, 0, stream>>>(ent, base, ent3, fbase, M, NB);

    const int mblocks16 = (M * 16 + 255) / 256;
    gather_splat_kernel<<<mblocks16, 256, 0, stream>>>(
        (const float4*)inp, ent3, fbase, (float4*)A, M);

    // --- blur phase: 6 ping-pong passes (A -> B -> A ... -> A) ---
    const float* src = A;
    float* dst = (float*)d_out;
    for (int j = 0; j < d1; ++j) {
        blur_kernel<<<mblocks16, 256, 0, stream>>>(
            (const float4*)src, (const int2*)(bn + (size_t)j * M * 2), (float4*)dst, M);
        float* tmp = (float*)src; src = dst; dst = tmp;
    }

    // d1=6 passes (even) -> final vals in A; slice reads A, writes d_out
    const int nblocks16 = (N * 16 + 255) / 256;
    slice_kernel<<<nblocks16, 256, 0, stream>>>(
        (const float4*)src, ws, os, (float4*)d_out, N, alpha);
}

// Round 7
// 272.258 us; speedup vs baseline: 3.2368x; 1.4983x over previous
//
#include <hip/hip_runtime.h>

#define CCH 64     // channels
#define BPB 256    // fine bins per coarse bucket
#define NBMAX 1024 // max coarse buckets (M/BPB = 1024 here)
#define ELPB 4096  // elements per partition block

typedef _Float16 half4v __attribute__((ext_vector_type(4)));   // 8 B
typedef _Float16 half8v __attribute__((ext_vector_type(8)));   // 16 B

__device__ __forceinline__ float4 f4zero() { return make_float4(0.f, 0.f, 0.f, 0.f); }

// ---- P1: per-block histogram of coarse buckets (LDS atomics only) ----
__global__ void p1_hist(const int* __restrict__ os, int* __restrict__ cnt,
                        int total, int nblk, int nb) {
    __shared__ int hist[NBMAX];
    int tid = threadIdx.x;
    for (int b = tid; b < nb; b += 256) hist[b] = 0;
    __syncthreads();
    int start = blockIdx.x * ELPB;
    for (int i = 0; i < ELPB / 256; ++i) {
        int idx = start + i * 256 + tid;
        if (idx < total) atomicAdd(&hist[os[idx] >> 8], 1);
    }
    __syncthreads();
    for (int b = tid; b < nb; b += 256)
        cnt[b * nblk + blockIdx.x] = hist[b];
}

// ---- P2a: per-bucket exclusive scan across blocks (one wave per bucket) ----
__global__ void p2a_scan(int* __restrict__ cnt, int* __restrict__ btot,
                         int nblk, int nb) {
    int wid  = (blockIdx.x * blockDim.x + threadIdx.x) >> 6;
    int lane = threadIdx.x & 63;
    if (wid >= nb) return;
    int running = 0;
    for (int c = 0; c < nblk; c += 64) {
        int in_r = (c + lane < nblk);
        int idx = wid * nblk + c + lane;
        int v = in_r ? cnt[idx] : 0;
        int s = v;
        for (int d = 1; d < 64; d <<= 1) { int t = __shfl_up(s, d); if (lane >= d) s += t; }
        if (in_r) cnt[idx] = running + s - v;
        running += __shfl(s, 63);
    }
    if (lane == 0) btot[wid] = running;
}

// ---- P2b: exclusive scan of bucket totals -> base[]; base[nb] = total ----
__global__ void p2b_base(const int* __restrict__ btot, int* __restrict__ base, int nb) {
    __shared__ int wtot[16];
    int tid = threadIdx.x, lane = tid & 63, w = tid >> 6;
    int v = (tid < nb) ? btot[tid] : 0;
    int s = v;
    for (int d = 1; d < 64; d <<= 1) { int t = __shfl_up(s, d); if (lane >= d) s += t; }
    if (lane == 63) wtot[w] = s;
    __syncthreads();
    if (w == 0) {
        int wv = (lane < 16) ? wtot[lane] : 0;
        int ss = wv;
        for (int d = 1; d < 16; d <<= 1) { int t = __shfl_up(ss, d); if (lane >= d) ss += t; }
        if (lane < 16) wtot[lane] = ss - wv;
    }
    __syncthreads();
    if (tid < nb) base[tid] = s - v + wtot[w];
    if (tid == nb - 1) base[nb] = s + wtot[w];   // grand total
}

// ---- P3: place packed (key, weight) into compact coarse-bucket segments ----
// key = (o & 255) << 18 | n   (n < 2^18); weight read SEQUENTIALLY from ws[idx]
__global__ void p3_scatter(const int* __restrict__ os, const float* __restrict__ ws,
                           const int* __restrict__ cnt, const int* __restrict__ base,
                           int2* __restrict__ ent, int total, int nblk, int nb, int d1) {
    __shared__ int cursor[NBMAX];
    int tid = threadIdx.x, blk = blockIdx.x;
    for (int b = tid; b < nb; b += 256)
        cursor[b] = base[b] + cnt[b * nblk + blk];
    __syncthreads();
    int start = blk * ELPB;
    for (int i = 0; i < ELPB / 256; ++i) {
        int idx = start + i * 256 + tid;
        if (idx < total) {
            int o = os[idx];
            int n = idx / d1;            // magic-mul
            float wv = ws[idx];          // sequential, coalesced
            int key = ((o & (BPB - 1)) << 18) | n;
            int d = atomicAdd(&cursor[o >> 8], 1);
            ent[d] = make_int2(key, __float_as_int(wv));
        }
    }
}

// ---- P3b: fine counting-sort within each bucket -> compact ent3 + fbase ----
__global__ void p3b_fine(const int2* __restrict__ ent, const int* __restrict__ base,
                         int2* __restrict__ ent3, int* __restrict__ fbase,
                         int M, int nb) {
    __shared__ int cur[BPB];
    __shared__ int wsum[4];
    int tid = threadIdx.x, lane = tid & 63, w = tid >> 6;
    int bkt = blockIdx.x;
    cur[tid] = 0;
    __syncthreads();
    int s = base[bkt], e = base[bkt + 1];
    for (int p = s + tid; p < e; p += 256)
        atomicAdd(&cur[ent[p].x >> 18], 1);
    __syncthreads();
    int v = cur[tid];
    int sc = v;
    for (int d = 1; d < 64; d <<= 1) { int t = __shfl_up(sc, d); if (lane >= d) sc += t; }
    if (lane == 63) wsum[w] = sc;
    __syncthreads();
    int woff = 0;
    for (int i = 0; i < w; ++i) woff += wsum[i];
    int excl = sc - v + woff;
    fbase[bkt * BPB + tid] = s + excl;
    __syncthreads();
    cur[tid] = excl;                    // reuse as intra-segment cursor
    __syncthreads();
    for (int p = s + tid; p < e; p += 256) {
        int2 kv = ent[p];
        int bl = kv.x >> 18;
        int pos = atomicAdd(&cur[bl], 1);          // LDS-scope
        ent3[s + pos] = make_int2(kv.x & 0x3FFFF, kv.y);
    }
    if (bkt == 0 && tid == 0) fbase[M] = base[nb];
}

// ---- Gather-splat: 16 lanes per lattice row, fp32 accumulate, fp16 store ----
__global__ void gather_splat_kernel(const float4* __restrict__ inp4,
                                    const int2* __restrict__ ent3,
                                    const int* __restrict__ fbase,
                                    half4v* __restrict__ valsh, int M) {
    int t = blockIdx.x * blockDim.x + threadIdx.x;
    int o = t >> 4;           // lattice row
    int l = t & 15;           // 4-channel slot within row
    if (o >= M) return;
    int lane  = threadIdx.x & 63;
    int gbase = lane & 48;    // first lane of this 16-lane group

    int s = fbase[o];
    int k = fbase[o + 1] - s;
    const int2* bucket = ent3 + s;

    int2 kv  = make_int2(0, 0);
    int2 kvh = make_int2(0, 0);
    if (l < k)      kv  = bucket[l];
    if (l + 16 < k) kvh = bucket[l + 16];

    float4 acc = f4zero();
    int klo = k < 16 ? k : 16;
    for (int i = 0; i < klo; ++i) {
        int   n = __shfl(kv.x, gbase + i);
        float w = __int_as_float(__shfl(kv.y, gbase + i));
        float4 v = inp4[(size_t)n * 16 + l];
        acc.x += w * v.x; acc.y += w * v.y; acc.z += w * v.z; acc.w += w * v.w;
    }
    int khi = k < 32 ? k : 32;
    for (int i = 16; i < khi; ++i) {
        int   n = __shfl(kvh.x, gbase + (i - 16));
        float w = __int_as_float(__shfl(kvh.y, gbase + (i - 16)));
        float4 v = inp4[(size_t)n * 16 + l];
        acc.x += w * v.x; acc.y += w * v.y; acc.z += w * v.z; acc.w += w * v.w;
    }
    for (int i = 32; i < k; ++i) {       // fully general tail, ~never
        int2 kvx = bucket[i];
        float w = __int_as_float(kvx.y);
        float4 v = inp4[(size_t)kvx.x * 16 + l];
        acc.x += w * v.x; acc.y += w * v.y; acc.z += w * v.z; acc.w += w * v.w;
    }
    half4v h;
    h[0] = (_Float16)acc.x; h[1] = (_Float16)acc.y;
    h[2] = (_Float16)acc.z; h[3] = (_Float16)acc.w;
    valsh[(size_t)o * 16 + l] = h;
}

// ---- Blur (fp16 buffers): 8 lanes/row, half8 per lane, fp32 math ----
__global__ void blur_kernel(const half8v* __restrict__ src,
                            const int2* __restrict__ bn,  // [M], 1-based pairs
                            half8v* __restrict__ dst, int M) {
    int t = blockIdx.x * blockDim.x + threadIdx.x;
    int m = t >> 3;
    int l = t & 7;
    if (m >= M) return;
    int2 nn = bn[m];
    half8v a  = src[(size_t)m * 8 + l];
    half8v z  = (half8v)(_Float16)0.f;
    half8v b1 = (nn.x > 0) ? src[(size_t)(nn.x - 1) * 8 + l] : z;
    half8v b2 = (nn.y > 0) ? src[(size_t)(nn.y - 1) * 8 + l] : z;
    half8v r;
#pragma unroll
    for (int i = 0; i < 8; ++i)
        r[i] = (_Float16)((float)a[i] + 0.5f * ((float)b1[i] + (float)b2[i]));
    dst[(size_t)m * 8 + l] = r;
}

// ---- Slice: out[n] = alpha * sum_j ws[n,j] * vals[os[n,j]]; fp16 vals ----
__global__ void slice_kernel(const half4v* __restrict__ valsh,
                             const float* __restrict__ ws,
                             const int* __restrict__ os,
                             float4* __restrict__ out4, int N, float alpha) {
    int t = blockIdx.x * blockDim.x + threadIdx.x;
    int n = t >> 4;
    int l = t & 15;
    if (n >= N) return;
    float4 acc = f4zero();
#pragma unroll
    for (int j = 0; j < 6; ++j) {
        float w = ws[n * 6 + j];
        int   o = os[n * 6 + j];
        half4v v = valsh[(size_t)o * 16 + l];
        acc.x += w * (float)v[0]; acc.y += w * (float)v[1];
        acc.z += w * (float)v[2]; acc.w += w * (float)v[3];
    }
    acc.x *= alpha; acc.y *= alpha; acc.z *= alpha; acc.w *= alpha;
    out4[(size_t)n * 16 + l] = acc;
}

extern "C" void kernel_launch(void* const* d_in, const int* in_sizes, int n_in,
                              void* d_out, int out_size, void* d_ws, size_t ws_size,
                              hipStream_t stream) {
    const float* inp = (const float*)d_in[0];
    const float* ws  = (const float*)d_in[1];
    const int*   os  = (const int*)d_in[2];
    const int*   bn  = (const int*)d_in[3];

    const int N  = in_sizes[0] / CCH;           // 262144
    const int d1 = in_sizes[1] / N;             // 6
    const int M  = in_sizes[3] / (d1 * 2);      // 262144
    const float alpha = 1.0f / (1.0f + exp2f(-(float)(d1 - 1)));

    // fp16 ping-pong vals buffers, both inside d_ws (32 MiB each)
    _Float16* A = (_Float16*)d_ws;
    _Float16* B = A + (size_t)M * CCH;

    const int total = N * d1;                       // 1572864
    const int NB    = (M + BPB - 1) / BPB;          // 1024
    const int NBLK  = (total + ELPB - 1) / ELPB;    // 384

    // Partition scratch inside d_out (dead before slice writes it), ~28 MB:
    int*  scratch = (int*)d_out;
    int2* ent   = (int2*)scratch;                   // [total] int2
    int*  cnt   = scratch + 2 * (size_t)total;      // [NB*NBLK]
    int*  btot  = cnt + NB * NBLK;                  // [NB]
    int*  base  = btot + NB;                        // [NB+1]
    int*  fbase = base + NB + 1;                    // [M+1]
    int2* ent3  = (int2*)(fbase + M + 1);           // [total] int2

    // --- splat phase (no global atomics, exact compact sort) ---
    p1_hist   <<<NBLK, 256, 0, stream>>>(os, cnt, total, NBLK, NB);
    p2a_scan  <<<(NB * 64 + 255) / 256, 256, 0, stream>>>(cnt, btot, NBLK, NB);
    p2b_base  <<<1, 1024, 0, stream>>>(btot, base, NB);
    p3_scatter<<<NBLK, 256, 0, stream>>>(os, ws, cnt, base, ent, total, NBLK, NB, d1);
    p3b_fine  <<<NB, 256, 0, stream>>>(ent, base, ent3, fbase, M, NB);

    const int gblocks = (M * 16 + 255) / 256;
    gather_splat_kernel<<<gblocks, 256, 0, stream>>>(
        (const float4*)inp, ent3, fbase, (half4v*)A, M);

    // --- blur phase: 6 ping-pong passes (A -> B -> A ... -> A) ---
    const int bblocks = (M * 8 + 255) / 256;
    const _Float16* src = A;
    _Float16* dst = B;
    for (int j = 0; j < d1; ++j) {
        blur_kernel<<<bblocks, 256, 0, stream>>>(
            (const half8v*)src, (const int2*)(bn + (size_t)j * M * 2), (half8v*)dst, M);
        _Float16* tmp = (_Float16*)src; src = dst; dst = tmp;
    }

    // d1=6 passes (even) -> final vals in A; slice reads A, writes d_out
    const int sblocks = (N * 16 + 255) / 256;
    slice_kernel<<<sblocks, 256, 0, stream>>>(
        (const half4v*)src, ws, os, (float4*)d_out, N, alpha);
}